// Round 5
// baseline (155.560 us; speedup 1.0000x reference)
//
#include <hip/hip_runtime.h>
#include <hip/hip_bf16.h>

#define IN_C  256
#define OUT_C 256
#define HH 56
#define WW 56
#define NN 32
#define XT_H 58
#define XT_W 64
#define WT_BYTES (8*9*256*32*2)  /* 1,179,648 B */

#define XS_BYTES 24576                /* 6 rows x 64 cols x 64B */
#define LDS_TOTAL (2*XS_BYTES)        /* 48 KiB -> 2 blocks/CU (reg-capped anyway) */

using short8 = __attribute__((ext_vector_type(8))) short;
using f32x4  = __attribute__((ext_vector_type(4))) float;

__device__ __forceinline__ void gload_lds16(const void* g, void* l) {
  __builtin_amdgcn_global_load_lds((const __attribute__((address_space(1))) void*)g,
                                   (__attribute__((address_space(3))) void*)l,
                                   16, 0, 0);
}

#define VMWAIT(N) asm volatile("s_waitcnt vmcnt(" #N ")" ::: "memory")

// ---------------------------------------------------------------------------
// Fused prepass: blocks [0, NN*XT_H) transpose/convert/pad x; the rest convert
// weights. One launch replaces k_wconv + k_xpad + k_xconv.
//   xt bf16 [n][hp=h+1][wp=w+1][ic]   (halo rows/cols zeroed)
//   wt bf16 [chunk(8)][tap(9)][oc(256)][ic5(32)]
// ---------------------------------------------------------------------------
__global__ void k_prep(const float* __restrict__ x, const float* __restrict__ w,
                       __hip_bfloat16* __restrict__ wt, __hip_bfloat16* __restrict__ xt) {
  const int b = blockIdx.x, tid = threadIdx.x;

  if (b >= NN * XT_H) {
    // ---- weight part: 576 blocks x 1024 elems (576*1024 == 256*256*9 exactly)
    const int base = (b - NN * XT_H) * 1024;
#pragma unroll
    for (int k = 0; k < 4; ++k) {
      int idx = base + k * 256 + tid;
      int kw = idx % 3; int t1 = idx / 3;
      int kh = t1 % 3;  int t2 = t1 / 3;
      int ic = t2 % IN_C; int oc = t2 / IN_C;
      int tap = kh * 3 + kw;
      wt[((((ic >> 5) * 9 + tap) * 256 + oc) * 32) + (ic & 31)] = __float2bfloat16(w[idx]);
    }
    return;
  }

  const int n = b / XT_H, hp = b % XT_H;
  __hip_bfloat16* row = xt + (size_t)(n * XT_H + hp) * XT_W * 256;

  if (hp == 0 || hp == XT_H - 1) {
    // top/bottom halo row: zero 64*256 bf16 = 32 KB
    int4 z; z.x = z.y = z.z = z.w = 0;
#pragma unroll
    for (int k = 0; k < 8; ++k) ((int4*)row)[k * 256 + tid] = z;
    return;
  }

  const int h = hp - 1;
  __shared__ __hip_bfloat16 tile[56][264];   // [w][ic], padded stride 528B

  {
    const int ic = tid;
    const float* src = x + (((size_t)n * IN_C + ic) * HH + h) * WW;
#pragma unroll
    for (int j = 0; j < 14; ++j) {
      float4 v = ((const float4*)src)[j];
      tile[4 * j + 0][ic] = __float2bfloat16(v.x);
      tile[4 * j + 1][ic] = __float2bfloat16(v.y);
      tile[4 * j + 2][ic] = __float2bfloat16(v.z);
      tile[4 * j + 3][ic] = __float2bfloat16(v.w);
    }
  }
  {
    // w-halo: wp=0 and wp=57..63 -> 8 cells x 512B = 256 thr x 16B
    int4 z; z.x = z.y = z.z = z.w = 0;
    int cell = tid >> 5, s = tid & 31;
    int wp = (cell == 0) ? 0 : (56 + cell);
    ((int4*)(row + (size_t)wp * 256))[s] = z;
  }
  __syncthreads();
  // store interior: 56 w x 32 segs of 8 ic, contiguous 16B per lane
#pragma unroll
  for (int k = 0; k < 7; ++k) {
    int e = k * 256 + tid;
    int wq = e >> 5, seg = e & 31;
    short8 v = *(const short8*)&tile[wq][seg * 8];
    *(short8*)(row + (size_t)(wq + 1) * 256 + seg * 8) = v;
  }
}

// ---------------------------------------------------------------------------
// main conv: block = 4 waves, tile 224 px x 128 oc; wave = 112 px x 64 oc.
// Weights: global(L2)->VGPR direct, 1-phase prefetch (wfA/wfB alternation).
// LDS holds only x (double-buffered). ONE barrier per ic-chunk (8 total).
// ---------------------------------------------------------------------------
__global__ __launch_bounds__(256, 2) void k_conv(
    const __hip_bfloat16* __restrict__ wt, const __hip_bfloat16* __restrict__ xt,
    const float* __restrict__ bias, float* __restrict__ out) {
  extern __shared__ __align__(16) char lds[];
  char* xs_c = lds;                    // [2][row6][col64][64B]

  const int tid  = threadIdx.x;
  const int wid  = tid >> 6, lane = tid & 63;
  const int cc   = lane & 15, g = lane >> 4;
  const int wn   = wid & 1,  wm = wid >> 1;

  // XCD-bijective swizzle (896 % 8 == 0)
  const int work = (blockIdx.x & 7) * 112 + (blockIdx.x >> 3);
  const int n  = work / 28;
  const int rem = work - n * 28;
  const int q  = rem >> 1, oh = rem & 1;
  const int h0 = q * 4;

  int xoff[7];
#pragma unroll
  for (int pt = 0; pt < 7; ++pt) {
    int p = wm * 112 + pt * 16 + cc;
    int rp = p / 56, wp = p - rp * 56;
    xoff[pt] = rp * 4096 + wp * 64 + g * 16;
  }
  const int ocb = oh * 128 + wn * 64;                       // wave's oc base
  const __hip_bfloat16* wlane = wt + (size_t)(ocb + cc) * 32 + g * 8;

  f32x4 acc[4][7];
#pragma unroll
  for (int a = 0; a < 4; ++a)
#pragma unroll
    for (int bb = 0; bb < 7; ++bb) acc[a][bb] = (f32x4){0.f, 0.f, 0.f, 0.f};

  const __hip_bfloat16* xtn = xt + (size_t)(n * XT_H + h0) * XT_W * 256;

  // x chunk staging: 24 strips of 1 KiB; 6 per wave (DMA, vmcnt-tracked)
  auto stage_x = [&](int buf, int ch) {
#pragma unroll
    for (int i = 0; i < 6; ++i) {
      int s = wid * 6 + i;
      int rowc = s >> 2, colq = s & 3;
      const __hip_bfloat16* src = xtn + (size_t)(rowc * 64 + colq * 16 + (lane >> 2)) * 256
                                      + ch * 32 + (lane & 3) * 8;
      gload_lds16(src, xs_c + buf * XS_BYTES + rowc * 4096 + colq * 1024);
    }
  };
  // weight fragments for phase ph = ch*9+tap: 4 x 16B coalesced (1 KiB/oct span)
  short8 wfA[4], wfB[4];
  auto loadw = [&](short8* dst, int ph) {
#pragma unroll
    for (int oct = 0; oct < 4; ++oct)
      dst[oct] = *(const short8*)(wlane + (size_t)ph * 8192 + oct * 512);
  };

  // prologue: x(0) strips, then weights for phase 0 (FIFO order matters)
  stage_x(0, 0);
  loadw(wfA, 0);

#define PHASE(ch_, tap_, WU_, WL_) do {                                               \
    if ((tap_) == 0) {                                                                \
      VMWAIT(4); /* newest 4 = next-phase wf loads => all x strips landed */          \
      __builtin_amdgcn_s_barrier();                                                   \
      if ((ch_) < 7) stage_x(((ch_) + 1) & 1, (ch_) + 1);                             \
    }                                                                                 \
    if (!((ch_) == 7 && (tap_) == 8)) loadw(WL_, (ch_) * 9 + (tap_) + 1);             \
    const char* xb = xs_c + (((ch_) & 1) ? XS_BYTES : 0);                             \
    short8 xf[7];                                                                     \
    _Pragma("unroll")                                                                 \
    for (int pt = 0; pt < 7; ++pt)                                                    \
      xf[pt] = *(const short8*)(xb + xoff[pt] + ((tap_) / 3) * 4096 + ((tap_) % 3) * 64); \
    __builtin_amdgcn_s_setprio(1);                                                    \
    _Pragma("unroll")                                                                 \
    for (int oct = 0; oct < 4; ++oct)                                                 \
      _Pragma("unroll")                                                               \
      for (int pt = 0; pt < 7; ++pt)                                                  \
        acc[oct][pt] = __builtin_amdgcn_mfma_f32_16x16x32_bf16(WU_[oct], xf[pt], acc[oct][pt], 0, 0, 0); \
    __builtin_amdgcn_s_setprio(0);                                                    \
  } while (0)

  for (int ch = 0; ch < 8; ++ch) {
    PHASE(ch, 0, wfA, wfB);
    PHASE(ch, 1, wfB, wfA);
    PHASE(ch, 2, wfA, wfB);
    PHASE(ch, 3, wfB, wfA);
    PHASE(ch, 4, wfA, wfB);
    PHASE(ch, 5, wfB, wfA);
    PHASE(ch, 6, wfA, wfB);
    PHASE(ch, 7, wfB, wfA);
    PHASE(ch, 8, wfA, wfB);
    // tap8 loaded next chunk's tap0 into wfB; realign for tap0's A-slot
#pragma unroll
    for (int oct = 0; oct < 4; ++oct) wfA[oct] = wfB[oct];
  }
#undef PHASE

  // epilogue: D row(4g+r)=oc, D col(cc)=pixel -> coalesced stores over cc
  int rp_[7], wp_[7];
#pragma unroll
  for (int pt = 0; pt < 7; ++pt) {
    int p = wm * 112 + pt * 16 + cc;
    rp_[pt] = p / 56; wp_[pt] = p - rp_[pt] * 56;
  }
#pragma unroll
  for (int oct = 0; oct < 4; ++oct) {
    const int oc0 = ocb + oct * 16 + 4 * g;
#pragma unroll
    for (int r = 0; r < 4; ++r) {
      const float bv = bias[oc0 + r];
      const size_t obase = ((size_t)n * OUT_C + (oc0 + r)) * (HH * WW);
#pragma unroll
      for (int pt = 0; pt < 7; ++pt)
        out[obase + (size_t)(h0 + rp_[pt]) * 56 + wp_[pt]] = acc[oct][pt][r] + bv;
    }
  }
}

extern "C" void kernel_launch(void* const* d_in, const int* in_sizes, int n_in,
                              void* d_out, int out_size, void* d_ws, size_t ws_size,
                              hipStream_t stream) {
  const float* x    = (const float*)d_in[0];
  const float* w    = (const float*)d_in[1];
  const float* bias = (const float*)d_in[2];
  float* out        = (float*)d_out;

  __hip_bfloat16* wt = (__hip_bfloat16*)d_ws;
  __hip_bfloat16* xt = (__hip_bfloat16*)((char*)d_ws + WT_BYTES);

  hipFuncSetAttribute((const void*)k_conv,
                      hipFuncAttributeMaxDynamicSharedMemorySize, LDS_TOTAL);

  k_prep<<<NN * XT_H + 576, 256, 0, stream>>>(x, w, wt, xt);
  k_conv<<<NN * 14 * 2, 256, LDS_TOTAL, stream>>>(wt, xt, bias, out);
}

// Round 6
// 138.078 us; speedup vs baseline: 1.1266x; 1.1266x over previous
//
#include <hip/hip_runtime.h>
#include <hip/hip_bf16.h>

#define IN_C  256
#define OUT_C 256
#define HH 56
#define WW 56
#define NN 32
#define XT_H 58
#define XT_W 64
#define WT_BYTES (8*9*256*32*2)  /* 1,179,648 B */

#define XS_BYTES 24576                /* 6 rows x 64 cols x 64B */
#define LDS_TOTAL (2*XS_BYTES)        /* 48 KiB */

using short8 = __attribute__((ext_vector_type(8))) short;
using f32x4  = __attribute__((ext_vector_type(4))) float;

__device__ __forceinline__ void gload_lds16(const void* g, void* l) {
  __builtin_amdgcn_global_load_lds((const __attribute__((address_space(1))) void*)g,
                                   (__attribute__((address_space(3))) void*)l,
                                   16, 0, 0);
}

#define VMWAIT(N) asm volatile("s_waitcnt vmcnt(" #N ")" ::: "memory")

// ---------------------------------------------------------------------------
// Fused prepass (unchanged from R5): x transpose/convert/pad + weight convert.
// ---------------------------------------------------------------------------
__global__ void k_prep(const float* __restrict__ x, const float* __restrict__ w,
                       __hip_bfloat16* __restrict__ wt, __hip_bfloat16* __restrict__ xt) {
  const int b = blockIdx.x, tid = threadIdx.x;

  if (b >= NN * XT_H) {
    const int base = (b - NN * XT_H) * 1024;
#pragma unroll
    for (int k = 0; k < 4; ++k) {
      int idx = base + k * 256 + tid;
      int kw = idx % 3; int t1 = idx / 3;
      int kh = t1 % 3;  int t2 = t1 / 3;
      int ic = t2 % IN_C; int oc = t2 / IN_C;
      int tap = kh * 3 + kw;
      wt[((((ic >> 5) * 9 + tap) * 256 + oc) * 32) + (ic & 31)] = __float2bfloat16(w[idx]);
    }
    return;
  }

  const int n = b / XT_H, hp = b % XT_H;
  __hip_bfloat16* row = xt + (size_t)(n * XT_H + hp) * XT_W * 256;

  if (hp == 0 || hp == XT_H - 1) {
    int4 z; z.x = z.y = z.z = z.w = 0;
#pragma unroll
    for (int k = 0; k < 8; ++k) ((int4*)row)[k * 256 + tid] = z;
    return;
  }

  const int h = hp - 1;
  __shared__ __hip_bfloat16 tile[56][264];

  {
    const int ic = tid;
    const float* src = x + (((size_t)n * IN_C + ic) * HH + h) * WW;
#pragma unroll
    for (int j = 0; j < 14; ++j) {
      float4 v = ((const float4*)src)[j];
      tile[4 * j + 0][ic] = __float2bfloat16(v.x);
      tile[4 * j + 1][ic] = __float2bfloat16(v.y);
      tile[4 * j + 2][ic] = __float2bfloat16(v.z);
      tile[4 * j + 3][ic] = __float2bfloat16(v.w);
    }
  }
  {
    int4 z; z.x = z.y = z.z = z.w = 0;
    int cell = tid >> 5, s = tid & 31;
    int wp = (cell == 0) ? 0 : (56 + cell);
    ((int4*)(row + (size_t)wp * 256))[s] = z;
  }
  __syncthreads();
#pragma unroll
  for (int k = 0; k < 7; ++k) {
    int e = k * 256 + tid;
    int wq = e >> 5, seg = e & 31;
    short8 v = *(const short8*)&tile[wq][seg * 8];
    *(short8*)(row + (size_t)(wq + 1) * 256 + seg * 8) = v;
  }
}

// ---------------------------------------------------------------------------
// main conv: block = 4 waves, 224 px x 128 oc; wave = 112 px x 64 oc.
// Weights global(L2)->VGPR with rolling 3-reg rotation (2-oct lookahead,
// 12 wf regs total -> no spill). LDS holds only x. 8 barriers total.
// ---------------------------------------------------------------------------
__global__ __launch_bounds__(256, 2) void k_conv(
    const __hip_bfloat16* __restrict__ wt, const __hip_bfloat16* __restrict__ xt,
    const float* __restrict__ bias, float* __restrict__ out) {
  extern __shared__ __align__(16) char lds[];
  char* xs_c = lds;                    // [2][row6][col64][64B]

  const int tid  = threadIdx.x;
  const int wid  = tid >> 6, lane = tid & 63;
  const int cc   = lane & 15, g = lane >> 4;
  const int wn   = wid & 1,  wm = wid >> 1;

  // XCD-bijective swizzle (896 % 8 == 0)
  const int work = (blockIdx.x & 7) * 112 + (blockIdx.x >> 3);
  const int n  = work / 28;
  const int rem = work - n * 28;
  const int q  = rem >> 1, oh = rem & 1;
  const int h0 = q * 4;

  int xoff[7];
#pragma unroll
  for (int pt = 0; pt < 7; ++pt) {
    int p = wm * 112 + pt * 16 + cc;
    int rp = p / 56, wp = p - rp * 56;
    xoff[pt] = rp * 4096 + wp * 64 + g * 16;
  }
  const int ocb = oh * 128 + wn * 64;
  const __hip_bfloat16* wlane = wt + (size_t)(ocb + cc) * 32 + g * 8;

  f32x4 acc[4][7];
#pragma unroll
  for (int a = 0; a < 4; ++a)
#pragma unroll
    for (int bb = 0; bb < 7; ++bb) acc[a][bb] = (f32x4){0.f, 0.f, 0.f, 0.f};

  const __hip_bfloat16* xtn = xt + (size_t)(n * XT_H + h0) * XT_W * 256;

  auto stage_x = [&](int buf, int ch) {
#pragma unroll
    for (int i = 0; i < 6; ++i) {
      int s = wid * 6 + i;
      int rowc = s >> 2, colq = s & 3;
      const __hip_bfloat16* src = xtn + (size_t)(rowc * 64 + colq * 16 + (lane >> 2)) * 256
                                      + ch * 32 + (lane & 3) * 8;
      gload_lds16(src, xs_c + buf * XS_BYTES + rowc * 4096 + colq * 1024);
    }
  };
  auto loadw1 = [&](int ph, int oct) -> short8 {
    return *(const short8*)(wlane + (size_t)ph * 8192 + oct * 512);
  };

  short8 wA, wB, wC;

  // prologue: x(0) DMA, pin FIFO position, then 2-oct weight lookahead
  stage_x(0, 0);
  __builtin_amdgcn_sched_barrier(0);
  wA = loadw1(0, 0);
  wB = loadw1(0, 1);

#define MFMA7(W_, oct_) do {                                                          \
    __builtin_amdgcn_s_setprio(1);                                                    \
    _Pragma("unroll")                                                                 \
    for (int pt = 0; pt < 7; ++pt)                                                    \
      acc[oct_][pt] = __builtin_amdgcn_mfma_f32_16x16x32_bf16(W_, xf[pt], acc[oct_][pt], 0, 0, 0); \
    __builtin_amdgcn_s_setprio(0);                                                    \
  } while (0)

  // Enter with T0_ = oct0, T1_ = oct1 of phase ph_. Exit: T1_ = next oct0,
  // T2_ = next oct1 -> caller rotates (T0,T1,T2) -> (T1,T2,T0).
#define PHASE(ph_, kh_, kw_, T0_, T1_, T2_) do {                                      \
    short8 xf[7];                                                                     \
    _Pragma("unroll")                                                                 \
    for (int pt = 0; pt < 7; ++pt)                                                    \
      xf[pt] = *(const short8*)(xb + xoff[pt] + (kh_) * 4096 + (kw_) * 64);           \
    T2_ = loadw1(ph_, 2);                                                             \
    MFMA7(T0_, 0);                                                                    \
    T0_ = loadw1(ph_, 3);                                                             \
    MFMA7(T1_, 1);                                                                    \
    T1_ = loadw1((ph_) + 1, 0);                                                       \
    MFMA7(T2_, 2);                                                                    \
    T2_ = loadw1((ph_) + 1, 1);                                                       \
    MFMA7(T0_, 3);                                                                    \
  } while (0)

  for (int ch = 0; ch < 8; ++ch) {
    if (ch == 0) { VMWAIT(2); } else { VMWAIT(8); }
    __builtin_amdgcn_s_barrier();
    if (ch < 7) {
      stage_x((ch + 1) & 1, ch + 1);
      __builtin_amdgcn_sched_barrier(0);
    }
    const char* xb = xs_c + ((ch & 1) ? XS_BYTES : 0);
    const int ph0 = ch * 9;
    PHASE(ph0 + 0, 0, 0, wA, wB, wC);
    PHASE(ph0 + 1, 0, 1, wB, wC, wA);
    PHASE(ph0 + 2, 0, 2, wC, wA, wB);
    PHASE(ph0 + 3, 1, 0, wA, wB, wC);
    PHASE(ph0 + 4, 1, 1, wB, wC, wA);
    PHASE(ph0 + 5, 1, 2, wC, wA, wB);
    PHASE(ph0 + 6, 2, 0, wA, wB, wC);
    PHASE(ph0 + 7, 2, 1, wB, wC, wA);
    PHASE(ph0 + 8, 2, 2, wC, wA, wB);
    // after 9 phases rotation returns to (wA, wB, wC) for the next chunk
  }
#undef PHASE
#undef MFMA7

  // epilogue: D row(4g+r)=oc, D col(cc)=pixel -> coalesced stores over cc
  int rp_[7], wp_[7];
#pragma unroll
  for (int pt = 0; pt < 7; ++pt) {
    int p = wm * 112 + pt * 16 + cc;
    rp_[pt] = p / 56; wp_[pt] = p - rp_[pt] * 56;
  }
#pragma unroll
  for (int oct = 0; oct < 4; ++oct) {
    const int oc0 = ocb + oct * 16 + 4 * g;
#pragma unroll
    for (int r = 0; r < 4; ++r) {
      const float bv = bias[oc0 + r];
      const size_t obase = ((size_t)n * OUT_C + (oc0 + r)) * (HH * WW);
#pragma unroll
      for (int pt = 0; pt < 7; ++pt)
        out[obase + (size_t)(h0 + rp_[pt]) * 56 + wp_[pt]] = acc[oct][pt][r] + bv;
    }
  }
}

extern "C" void kernel_launch(void* const* d_in, const int* in_sizes, int n_in,
                              void* d_out, int out_size, void* d_ws, size_t ws_size,
                              hipStream_t stream) {
  const float* x    = (const float*)d_in[0];
  const float* w    = (const float*)d_in[1];
  const float* bias = (const float*)d_in[2];
  float* out        = (float*)d_out;

  __hip_bfloat16* wt = (__hip_bfloat16*)d_ws;
  __hip_bfloat16* xt = (__hip_bfloat16*)((char*)d_ws + WT_BYTES);

  hipFuncSetAttribute((const void*)k_conv,
                      hipFuncAttributeMaxDynamicSharedMemorySize, LDS_TOTAL);

  k_prep<<<NN * XT_H + 576, 256, 0, stream>>>(x, w, wt, xt);
  k_conv<<<NN * 14 * 2, 256, LDS_TOTAL, stream>>>(wt, xt, bias, out);
}

// Round 7
// 137.531 us; speedup vs baseline: 1.1311x; 1.0040x over previous
//
#include <hip/hip_runtime.h>
#include <hip/hip_bf16.h>

#define IN_C  256
#define OUT_C 256
#define HH 56
#define WW 56
#define NN 32
#define XT_H 58
#define XT_W 64
#define WT_BYTES (8*9*256*32*2)  /* 1,179,648 B */

#define XS_BYTES 24576                /* 6 rows x 64 cols x 64B */
#define LDS_TOTAL (2*XS_BYTES)        /* 48 KiB */

using short8 = __attribute__((ext_vector_type(8))) short;
using f32x4  = __attribute__((ext_vector_type(4))) float;

__device__ __forceinline__ void gload_lds16(const void* g, void* l) {
  __builtin_amdgcn_global_load_lds((const __attribute__((address_space(1))) void*)g,
                                   (__attribute__((address_space(3))) void*)l,
                                   16, 0, 0);
}

#define VMWAIT(N) asm volatile("s_waitcnt vmcnt(" #N ")" ::: "memory")

// ---------------------------------------------------------------------------
// Fused prepass (unchanged): x transpose/convert/pad + weight convert.
// ---------------------------------------------------------------------------
__global__ void k_prep(const float* __restrict__ x, const float* __restrict__ w,
                       __hip_bfloat16* __restrict__ wt, __hip_bfloat16* __restrict__ xt) {
  const int b = blockIdx.x, tid = threadIdx.x;

  if (b >= NN * XT_H) {
    const int base = (b - NN * XT_H) * 1024;
#pragma unroll
    for (int k = 0; k < 4; ++k) {
      int idx = base + k * 256 + tid;
      int kw = idx % 3; int t1 = idx / 3;
      int kh = t1 % 3;  int t2 = t1 / 3;
      int ic = t2 % IN_C; int oc = t2 / IN_C;
      int tap = kh * 3 + kw;
      wt[((((ic >> 5) * 9 + tap) * 256 + oc) * 32) + (ic & 31)] = __float2bfloat16(w[idx]);
    }
    return;
  }

  const int n = b / XT_H, hp = b % XT_H;
  __hip_bfloat16* row = xt + (size_t)(n * XT_H + hp) * XT_W * 256;

  if (hp == 0 || hp == XT_H - 1) {
    int4 z; z.x = z.y = z.z = z.w = 0;
#pragma unroll
    for (int k = 0; k < 8; ++k) ((int4*)row)[k * 256 + tid] = z;
    return;
  }

  const int h = hp - 1;
  __shared__ __hip_bfloat16 tile[56][264];

  {
    const int ic = tid;
    const float* src = x + (((size_t)n * IN_C + ic) * HH + h) * WW;
#pragma unroll
    for (int j = 0; j < 14; ++j) {
      float4 v = ((const float4*)src)[j];
      tile[4 * j + 0][ic] = __float2bfloat16(v.x);
      tile[4 * j + 1][ic] = __float2bfloat16(v.y);
      tile[4 * j + 2][ic] = __float2bfloat16(v.z);
      tile[4 * j + 3][ic] = __float2bfloat16(v.w);
    }
  }
  {
    int4 z; z.x = z.y = z.z = z.w = 0;
    int cell = tid >> 5, s = tid & 31;
    int wp = (cell == 0) ? 0 : (56 + cell);
    ((int4*)(row + (size_t)wp * 256))[s] = z;
  }
  __syncthreads();
#pragma unroll
  for (int k = 0; k < 7; ++k) {
    int e = k * 256 + tid;
    int wq = e >> 5, seg = e & 31;
    short8 v = *(const short8*)&tile[wq][seg * 8];
    *(short8*)(row + (size_t)(wq + 1) * 256 + seg * 8) = v;
  }
}

// ---------------------------------------------------------------------------
// main conv: block = 4 waves, 224 px x 128 oc; wave = 112 px x 64 oc.
// Weights global(L2)->VGPR, 4-slot pipeline, lookahead = 3 MFMA groups
// (~407 cyc). xf double-buffered: phase p+1's ds_reads interleave with
// phase p's MFMA groups. 8 barriers total; vmcnt(3) at chunk boundary.
// ---------------------------------------------------------------------------
__global__ __launch_bounds__(256, 2) void k_conv(
    const __hip_bfloat16* __restrict__ wt, const __hip_bfloat16* __restrict__ xt,
    const float* __restrict__ bias, float* __restrict__ out) {
  extern __shared__ __align__(16) char lds[];
  char* xs_c = lds;                    // [2][row6][col64][64B]

  const int tid  = threadIdx.x;
  const int wid  = tid >> 6, lane = tid & 63;
  const int cc   = lane & 15, g = lane >> 4;
  const int wn   = wid & 1,  wm = wid >> 1;

  // XCD-bijective swizzle (896 % 8 == 0)
  const int work = (blockIdx.x & 7) * 112 + (blockIdx.x >> 3);
  const int n  = work / 28;
  const int rem = work - n * 28;
  const int q  = rem >> 1, oh = rem & 1;
  const int h0 = q * 4;

  int xoff[7];
#pragma unroll
  for (int pt = 0; pt < 7; ++pt) {
    int p = wm * 112 + pt * 16 + cc;
    int rp = p / 56, wp = p - rp * 56;
    xoff[pt] = rp * 4096 + wp * 64 + g * 16;
  }
  const int ocb = oh * 128 + wn * 64;
  const __hip_bfloat16* wlane = wt + (size_t)(ocb + cc) * 32 + g * 8;

  f32x4 acc[4][7];
#pragma unroll
  for (int a = 0; a < 4; ++a)
#pragma unroll
    for (int bb = 0; bb < 7; ++bb) acc[a][bb] = (f32x4){0.f, 0.f, 0.f, 0.f};

  const __hip_bfloat16* xtn = xt + (size_t)(n * XT_H + h0) * XT_W * 256;

  auto stage_x = [&](int buf, int ch) {
#pragma unroll
    for (int i = 0; i < 6; ++i) {
      int s = wid * 6 + i;
      int rowc = s >> 2, colq = s & 3;
      const __hip_bfloat16* src = xtn + (size_t)(rowc * 64 + colq * 16 + (lane >> 2)) * 256
                                      + ch * 32 + (lane & 3) * 8;
      gload_lds16(src, xs_c + buf * XS_BYTES + rowc * 4096 + colq * 1024);
    }
  };
  auto loadw1 = [&](int ph, int oct) -> short8 {
    return *(const short8*)(wlane + (size_t)ph * 8192 + oct * 512);
  };

  short8 wA, wB, wC, wD;
  short8 xfA[7], xfB[7];

  // prologue: x(0) DMA, then 3-group weight lookahead (FIFO: DMA oldest)
  stage_x(0, 0);
  __builtin_amdgcn_sched_barrier(0);
  wA = loadw1(0, 0);
  wB = loadw1(0, 1);
  wC = loadw1(0, 2);

#define MFMA7(X_, W_, oct_) do {                                                      \
    __builtin_amdgcn_s_setprio(1);                                                    \
    _Pragma("unroll")                                                                 \
    for (int pt = 0; pt < 7; ++pt)                                                    \
      acc[oct_][pt] = __builtin_amdgcn_mfma_f32_16x16x32_bf16(W_, X_[pt], acc[oct_][pt], 0, 0, 0); \
    __builtin_amdgcn_s_setprio(0);                                                    \
  } while (0)

#define LDX(i_, kh_, kw_) (*(const short8*)(xb + xoff[i_] + (kh_) * 4096 + (kw_) * 64))

  // phase: consume XU_ (already in regs), prefetch next phase's frags into XL_
  // at coords (nkh_, nkw_); weight pipeline slides by one phase.
#define PHASE(ph_, XU_, XL_, nkh_, nkw_) do {                                         \
    wD = loadw1(ph_, 3);                                                              \
    XL_[0] = LDX(0, nkh_, nkw_); XL_[1] = LDX(1, nkh_, nkw_);                         \
    MFMA7(XU_, wA, 0);                                                                \
    wA = loadw1((ph_) + 1, 0);                                                        \
    XL_[2] = LDX(2, nkh_, nkw_); XL_[3] = LDX(3, nkh_, nkw_);                         \
    MFMA7(XU_, wB, 1);                                                                \
    wB = loadw1((ph_) + 1, 1);                                                        \
    XL_[4] = LDX(4, nkh_, nkw_); XL_[5] = LDX(5, nkh_, nkw_);                         \
    MFMA7(XU_, wC, 2);                                                                \
    wC = loadw1((ph_) + 1, 2);                                                        \
    XL_[6] = LDX(6, nkh_, nkw_);                                                      \
    MFMA7(XU_, wD, 3);                                                                \
  } while (0)

  // last phase of a chunk: no xf prefetch (next chunk's LDS not ready yet)
#define PHASE_END(ph_, XU_) do {                                                      \
    wD = loadw1(ph_, 3);                                                              \
    MFMA7(XU_, wA, 0);                                                                \
    wA = loadw1((ph_) + 1, 0);                                                        \
    MFMA7(XU_, wB, 1);                                                                \
    wB = loadw1((ph_) + 1, 1);                                                        \
    MFMA7(XU_, wC, 2);                                                                \
    wC = loadw1((ph_) + 1, 2);                                                        \
    MFMA7(XU_, wD, 3);                                                                \
  } while (0)

  for (int ch = 0; ch < 8; ++ch) {
    // only the 3 newest (rolling w loads) may stay in flight -> x DMA drained
    VMWAIT(3);
    __builtin_amdgcn_s_barrier();
    if (ch < 7) {
      stage_x((ch + 1) & 1, ch + 1);
      __builtin_amdgcn_sched_barrier(0);
    }
    const char* xb = xs_c + ((ch & 1) ? XS_BYTES : 0);
    const int ph0 = ch * 9;
    // tap0 fragments loaded synchronously (once per chunk)
#pragma unroll
    for (int pt = 0; pt < 7; ++pt) xfA[pt] = LDX(pt, 0, 0);
    PHASE(ph0 + 0, xfA, xfB, 0, 1);
    PHASE(ph0 + 1, xfB, xfA, 0, 2);
    PHASE(ph0 + 2, xfA, xfB, 1, 0);
    PHASE(ph0 + 3, xfB, xfA, 1, 1);
    PHASE(ph0 + 4, xfA, xfB, 1, 2);
    PHASE(ph0 + 5, xfB, xfA, 2, 0);
    PHASE(ph0 + 6, xfA, xfB, 2, 1);
    PHASE(ph0 + 7, xfB, xfA, 2, 2);
    PHASE_END(ph0 + 8, xfA);
  }
#undef PHASE
#undef PHASE_END
#undef LDX
#undef MFMA7

  // epilogue: D row(4g+r)=oc, D col(cc)=pixel -> coalesced stores over cc
  int rp_[7], wp_[7];
#pragma unroll
  for (int pt = 0; pt < 7; ++pt) {
    int p = wm * 112 + pt * 16 + cc;
    rp_[pt] = p / 56; wp_[pt] = p - rp_[pt] * 56;
  }
#pragma unroll
  for (int oct = 0; oct < 4; ++oct) {
    const int oc0 = ocb + oct * 16 + 4 * g;
#pragma unroll
    for (int r = 0; r < 4; ++r) {
      const float bv = bias[oc0 + r];
      const size_t obase = ((size_t)n * OUT_C + (oc0 + r)) * (HH * WW);
#pragma unroll
      for (int pt = 0; pt < 7; ++pt)
        out[obase + (size_t)(h0 + rp_[pt]) * 56 + wp_[pt]] = acc[oct][pt][r] + bv;
    }
  }
}

extern "C" void kernel_launch(void* const* d_in, const int* in_sizes, int n_in,
                              void* d_out, int out_size, void* d_ws, size_t ws_size,
                              hipStream_t stream) {
  const float* x    = (const float*)d_in[0];
  const float* w    = (const float*)d_in[1];
  const float* bias = (const float*)d_in[2];
  float* out        = (float*)d_out;

  __hip_bfloat16* wt = (__hip_bfloat16*)d_ws;
  __hip_bfloat16* xt = (__hip_bfloat16*)((char*)d_ws + WT_BYTES);

  hipFuncSetAttribute((const void*)k_conv,
                      hipFuncAttributeMaxDynamicSharedMemorySize, LDS_TOTAL);

  k_prep<<<NN * XT_H + 576, 256, 0, stream>>>(x, w, wt, xt);
  k_conv<<<NN * 14 * 2, 256, LDS_TOTAL, stream>>>(wt, xt, bias, out);
}